// Round 16
// baseline (202.514 us; speedup 1.0000x reference)
//
#include <hip/hip_runtime.h>

// Problem constants (Attention_27668179320916)
#define Bn   2
#define Sn   512
#define DIMn 4096
#define HQn  32
#define HKVn 8
#define HDn  128
#define NPAIR 64
#define KVN  (HKVn * HDn)              // 1024
#define NALL (DIMn + 2 * KVN)          // 6144 fused QKV output rows of W
#define SCALE 11.313708498984761f      // scores / (hd**-0.5) == * sqrt(128) (faithful to ref)

typedef short bf16x8 __attribute__((ext_vector_type(8)));
typedef float f32x4 __attribute__((ext_vector_type(4)));
typedef unsigned short ushort8 __attribute__((ext_vector_type(8)));
typedef signed char char8 __attribute__((ext_vector_type(8)));
typedef int i32x4 __attribute__((ext_vector_type(4)));

__device__ __forceinline__ unsigned short f2bf_rne(float f) {
  unsigned u = __builtin_bit_cast(unsigned, f);
  u += 0x7fffu + ((u >> 16) & 1u);
  return (unsigned short)(u >> 16);
}
__device__ __forceinline__ float bf2f(unsigned short h) {
  unsigned u = ((unsigned)h) << 16;
  return __builtin_bit_cast(float, u);
}
__device__ __forceinline__ void split_bf16(float x, unsigned short& hi, unsigned short& lo) {
  unsigned u = __builtin_bit_cast(unsigned, x);
  hi = (unsigned short)(u >> 16);
  float hf = __builtin_bit_cast(float, u & 0xffff0000u);
  lo = (unsigned short)(__builtin_bit_cast(unsigned, x - hf) >> 16);
}
__device__ __forceinline__ void gload16(const void* g, void* lds) {
  __builtin_amdgcn_global_load_lds(
      (const __attribute__((address_space(1))) unsigned int*)g,
      (__attribute__((address_space(3))) unsigned int*)lds, 16, 0, 0);
}

// ---------------------------------------------------------------------------
// quant_rows (r15, verbatim): rows 0..1023 = x split-i8; 1024..7167 =
// [wq|wk|wv] split-i8; 7168..11263 = wo single-plane i8 (per-row scale sWo).
// Block 0 thread 0 zero-inits the V-amax slot (consumed by vamax_k).
// ---------------------------------------------------------------------------
__global__ __launch_bounds__(256) void quant_rows(
    const float* __restrict__ x, const float* __restrict__ wq,
    const float* __restrict__ wk, const float* __restrict__ wv,
    const float* __restrict__ wo,
    signed char* __restrict__ xh8, signed char* __restrict__ xl8,
    signed char* __restrict__ wh8, signed char* __restrict__ wl8,
    signed char* __restrict__ wo8,
    float* __restrict__ sA, float* __restrict__ sW, float* __restrict__ sWo,
    unsigned* __restrict__ amaxp)
{
  const int r = blockIdx.x;          // 0..11263
  const int t = threadIdx.x;
  if (r == 0 && t == 0) *amaxp = 0u; // init for vamax_k's atomicMax (stream-ordered)

  __shared__ float wm[4];

  if (r >= 1024 + NALL) {            // ---- wo rows: single-plane i8 ----
    int wr2 = r - 1024 - NALL;       // 0..4095
    const float* src = wo + (size_t)wr2 * DIMn;
    float4 v[4];
    float am = 0.f;
    #pragma unroll
    for (int j = 0; j < 4; ++j) {
      v[j] = ((const float4*)src)[t + j * 256];
      am = fmaxf(am, fmaxf(fmaxf(fabsf(v[j].x), fabsf(v[j].y)),
                           fmaxf(fabsf(v[j].z), fabsf(v[j].w))));
    }
    #pragma unroll
    for (int o = 1; o < 64; o <<= 1) am = fmaxf(am, __shfl_xor(am, o));
    if ((t & 63) == 0) wm[t >> 6] = am;
    __syncthreads();
    am = fmaxf(fmaxf(wm[0], wm[1]), fmaxf(wm[2], wm[3]));
    const float inv = (am > 0.f) ? 127.0f / am : 0.f;
    if (t == 0) sWo[wr2] = am * (1.0f / 127.0f);
    signed char* dst = wo8 + (size_t)wr2 * DIMn;
    #pragma unroll
    for (int j = 0; j < 4; ++j) {
      float fv[4] = {v[j].x, v[j].y, v[j].z, v[j].w};
      char4 q;
      q.x = (signed char)__float2int_rn(fv[0] * inv);
      q.y = (signed char)__float2int_rn(fv[1] * inv);
      q.z = (signed char)__float2int_rn(fv[2] * inv);
      q.w = (signed char)__float2int_rn(fv[3] * inv);
      ((char4*)dst)[t + j * 256] = q;
    }
    return;
  }

  const float* src; signed char* ph; signed char* pl; float* ps; size_t prow;
  if (r < 1024) {
    src = x + (size_t)r * DIMn; ph = xh8; pl = xl8; ps = sA + r; prow = (size_t)r * DIMn;
  } else {
    int wr_ = r - 1024;
    ps = sW + wr_; ph = wh8; pl = wl8; prow = (size_t)wr_ * DIMn;
    if (wr_ < DIMn)            src = wq + (size_t)wr_ * DIMn;
    else if (wr_ < DIMn + KVN) src = wk + (size_t)(wr_ - DIMn) * DIMn;
    else                       src = wv + (size_t)(wr_ - DIMn - KVN) * DIMn;
  }
  float4 v[4];
  float am = 0.f;
  #pragma unroll
  for (int j = 0; j < 4; ++j) {
    v[j] = ((const float4*)src)[t + j * 256];
    am = fmaxf(am, fmaxf(fmaxf(fabsf(v[j].x), fabsf(v[j].y)),
                         fmaxf(fabsf(v[j].z), fabsf(v[j].w))));
  }
  #pragma unroll
  for (int o = 1; o < 64; o <<= 1) am = fmaxf(am, __shfl_xor(am, o));
  if ((t & 63) == 0) wm[t >> 6] = am;
  __syncthreads();
  am = fmaxf(fmaxf(wm[0], wm[1]), fmaxf(wm[2], wm[3]));
  const float inv = (am > 0.f) ? 32512.0f / am : 0.f;
  if (t == 0) *ps = am * (1.0f / 32512.0f);
  #pragma unroll
  for (int j = 0; j < 4; ++j) {
    float fv[4] = {v[j].x, v[j].y, v[j].z, v[j].w};
    signed char hh[4], ll[4];
    #pragma unroll
    for (int e = 0; e < 4; ++e) {
      int q = __float2int_rn(fv[e] * inv);      // |q| <= 32512
      int hi = (q + 128) >> 8;                  // hi in [-127,127]
      hh[e] = (signed char)hi;
      ll[e] = (signed char)(q - (hi << 8));     // lo in [-128,127]
    }
    ((char4*)(ph + prow))[t + j * 256] = make_char4(hh[0], hh[1], hh[2], hh[3]);
    ((char4*)(pl + prow))[t + j * 256] = make_char4(ll[0], ll[1], ll[2], ll[3]);
  }
}

// ---------------------------------------------------------------------------
// vamax_k (r16): amax over Vw (bf16, 1M elems, 2 MB) -> amaxp via atomicMax.
// Decoupled from qkv (r15's in-epilogue version perturbed qkv's codegen,
// 91.8 -> 112.5us — rule #19). Order-independent max => deterministic.
// ---------------------------------------------------------------------------
__global__ __launch_bounds__(256) void vamax_k(
    const unsigned short* __restrict__ Vw, unsigned* __restrict__ amaxp, int n8)
{
  __shared__ float wm[4];
  float am = 0.f;
  for (int i = blockIdx.x * blockDim.x + threadIdx.x; i < n8; i += gridDim.x * blockDim.x) {
    ushort8 v = ((const ushort8*)Vw)[i];
    #pragma unroll
    for (int j = 0; j < 8; ++j) am = fmaxf(am, fabsf(bf2f(v[j])));
  }
  #pragma unroll
  for (int o = 1; o < 64; o <<= 1) am = fmaxf(am, __shfl_xor(am, o));
  if ((threadIdx.x & 63) == 0) wm[threadIdx.x >> 6] = am;
  __syncthreads();
  if (threadIdx.x == 0) {
    float m = fmaxf(fmaxf(wm[0], wm[1]), fmaxf(wm[2], wm[3]));
    if (m > 0.f) atomicMax(amaxp, __builtin_bit_cast(unsigned, m)); // m>=0: bit==numeric order
  }
}

// ---------------------------------------------------------------------------
// qkv_gemm_i8 (r13 BIT-EXACT revert — proven 91.8us): i8-split fused QKV,
// 3-phase counted-vmcnt pipeline, block 128x96, grid 512 = 2/CU,
// zero-conflict slot^(R&7) geometry, W-grouped XCD swizzle.
// ---------------------------------------------------------------------------
__global__ __launch_bounds__(256, 2) void qkv_gemm_i8(
    const signed char* __restrict__ Ah, const signed char* __restrict__ Al,
    const signed char* __restrict__ Wh, const signed char* __restrict__ Wl,
    const float* __restrict__ sA, const float* __restrict__ sW,
    float* __restrict__ CQ, float* __restrict__ CK, unsigned short* __restrict__ CV)
{
  constexpr int KS = 64;
  constexpr int TILEB = 224 * 128;            // 28672 B
  __shared__ __align__(16) signed char Ls[2][TILEB];

  const int t = threadIdx.x, w = t >> 6, lane = t & 63;
  const int bid = blockIdx.x;                 // grid 512 = 8 xcd x 64
  const int s = (bid & 7) * 64 + (bid >> 3);
  const int bx = s >> 3, by = s & 7;
  const int bm = by * 128, bn = bx * 96;

  const signed char* gsrc[7];
  int ldst[7];
  #pragma unroll
  for (int j = 0; j < 4; ++j) {               // A rows 0..127
    int u = j * 256 + t;
    int R = u >> 3, slot = u & 7;
    int q = slot ^ (R & 7);
    gsrc[j] = (q < 4 ? Ah : Al) + (size_t)(bm + R) * DIMn + (q & 3) * 16;
    ldst[j] = u * 16;
  }
  #pragma unroll
  for (int j = 4; j < 7; ++j) {               // B batches aligned to fn
    int base0 = (j - 4) * 16;                 // 0,16,32
    int rb = base0 + (t >> 3) + ((t < 128) ? 0 : 32);
    int slot = t & 7;
    int q = slot ^ (rb & 7);
    gsrc[j] = (q < 4 ? Wh : Wl) + (size_t)(bn + rb) * DIMn + (q & 3) * 16;
    ldst[j] = (128 + rb) * 128 + slot * 16;
  }

  const int wr = w >> 1, wc = w & 1;
  const int rl = lane & 15, kh = lane >> 4;
  int aoff[4], boff[3];
  #pragma unroll
  for (int fm = 0; fm < 4; ++fm) {
    int R = wr * 64 + fm * 16 + rl;
    aoff[fm] = R * 128 + ((kh ^ (R & 7)) * 16);
  }
  #pragma unroll
  for (int fn = 0; fn < 3; ++fn) {
    int R = 128 + wc * 48 + fn * 16 + rl;
    boff[fn] = R * 128 + ((kh ^ (R & 7)) * 16);
  }

  i32x4 acc1[4][3], acc2[4][3];
  #pragma unroll
  for (int i = 0; i < 4; ++i)
  #pragma unroll
    for (int j = 0; j < 3; ++j) {
      acc1[i][j] = (i32x4){0, 0, 0, 0};
      acc2[i][j] = (i32x4){0, 0, 0, 0};
    }

  const int nt = DIMn / KS;                   // 64
  #pragma unroll
  for (int j = 0; j < 7; ++j) gload16(gsrc[j], &Ls[0][ldst[j]]);

  for (int tt = 0; tt < nt; ++tt) {
    const int buf = tt & 1, nbuf = buf ^ 1;
    const bool more = (tt + 1 < nt);
    const signed char* Lp = &Ls[buf][0];
    i32x4 ah[4], al[4];

    // ---- phase 0: A + B fn0 ----
    asm volatile("s_waitcnt vmcnt(2)" ::: "memory");
    __builtin_amdgcn_s_barrier();
    __builtin_amdgcn_sched_barrier(0);
    if (more) {
      #pragma unroll
      for (int j = 0; j < 5; ++j)
        gload16(gsrc[j] + (size_t)(tt + 1) * KS, &Ls[nbuf][ldst[j]]);
    }
    #pragma unroll
    for (int fm = 0; fm < 4; ++fm) {
      ah[fm] = *(const i32x4*)(Lp + aoff[fm]);
      al[fm] = *(const i32x4*)(Lp + (aoff[fm] ^ 64));
    }
    {
      i32x4 bh = *(const i32x4*)(Lp + boff[0]);
      i32x4 bl = *(const i32x4*)(Lp + (boff[0] ^ 64));
      __builtin_amdgcn_s_setprio(1);
      #pragma unroll
      for (int fm = 0; fm < 4; ++fm) {
        acc1[fm][0] = __builtin_amdgcn_mfma_i32_16x16x64_i8(ah[fm], bh, acc1[fm][0], 0, 0, 0);
        acc2[fm][0] = __builtin_amdgcn_mfma_i32_16x16x64_i8(ah[fm], bl, acc2[fm][0], 0, 0, 0);
        acc2[fm][0] = __builtin_amdgcn_mfma_i32_16x16x64_i8(al[fm], bh, acc2[fm][0], 0, 0, 0);
      }
      __builtin_amdgcn_s_setprio(0);
    }

    // ---- phase 1: B fn1 ----
    if (more) asm volatile("s_waitcnt vmcnt(6)" ::: "memory");
    else      asm volatile("s_waitcnt vmcnt(1)" ::: "memory");
    __builtin_amdgcn_s_barrier();
    __builtin_amdgcn_sched_barrier(0);
    if (more)
      gload16(gsrc[5] + (size_t)(tt + 1) * KS, &Ls[nbuf][ldst[5]]);
    {
      i32x4 bh = *(const i32x4*)(Lp + boff[1]);
      i32x4 bl = *(const i32x4*)(Lp + (boff[1] ^ 64));
      __builtin_amdgcn_s_setprio(1);
      #pragma unroll
      for (int fm = 0; fm < 4; ++fm) {
        acc1[fm][1] = __builtin_amdgcn_mfma_i32_16x16x64_i8(ah[fm], bh, acc1[fm][1], 0, 0, 0);
        acc2[fm][1] = __builtin_amdgcn_mfma_i32_16x16x64_i8(ah[fm], bl, acc2[fm][1], 0, 0, 0);
        acc2[fm][1] = __builtin_amdgcn_mfma_i32_16x16x64_i8(al[fm], bh, acc2[fm][1], 0, 0, 0);
      }
      __builtin_amdgcn_s_setprio(0);
    }

    // ---- phase 2: B fn2 ----
    if (more) asm volatile("s_waitcnt vmcnt(6)" ::: "memory");
    else      asm volatile("s_waitcnt vmcnt(0)" ::: "memory");
    __builtin_amdgcn_s_barrier();
    __builtin_amdgcn_sched_barrier(0);
    if (more)
      gload16(gsrc[6] + (size_t)(tt + 1) * KS, &Ls[nbuf][ldst[6]]);
    {
      i32x4 bh = *(const i32x4*)(Lp + boff[2]);
      i32x4 bl = *(const i32x4*)(Lp + (boff[2] ^ 64));
      __builtin_amdgcn_s_setprio(1);
      #pragma unroll
      for (int fm = 0; fm < 4; ++fm) {
        acc1[fm][2] = __builtin_amdgcn_mfma_i32_16x16x64_i8(ah[fm], bh, acc1[fm][2], 0, 0, 0);
        acc2[fm][2] = __builtin_amdgcn_mfma_i32_16x16x64_i8(ah[fm], bl, acc2[fm][2], 0, 0, 0);
        acc2[fm][2] = __builtin_amdgcn_mfma_i32_16x16x64_i8(al[fm], bh, acc2[fm][2], 0, 0, 0);
      }
      __builtin_amdgcn_s_setprio(0);
    }
  }

  // epilogue: 16x16 C/D layout col=lane&15, row=(lane>>4)*4+reg (m89)
  #pragma unroll
  for (int fn = 0; fn < 3; ++fn) {
    const int colW = bn + wc * 48 + fn * 16 + rl;
    const float sw = sW[colW];
    #pragma unroll
    for (int fm = 0; fm < 4; ++fm) {
      #pragma unroll
      for (int j = 0; j < 4; ++j) {
        int grow = bm + wr * 64 + fm * 16 + kh * 4 + j;
        float val = sA[grow] * sw *
            fmaf((float)acc1[fm][fn][j], 65536.0f, (float)acc2[fm][fn][j] * 256.0f);
        if (colW < DIMn)            CQ[(size_t)grow * DIMn + colW] = val;
        else if (colW < DIMn + KVN) CK[(size_t)grow * KVN + (colW - DIMn)] = val;
        else                        CV[(size_t)grow * KVN + (colW - DIMn - KVN)] = f2bf_rne(val);
      }
    }
  }
}

// ---------------------------------------------------------------------------
// oproj_i8 (r14, verbatim): O-proj from single-plane i8, KS=128, 3-buf
// counted-vmcnt, zero-conflict geometry, grid 512 = 2/CU, XCD swizzle.
// out = (amaxV/127) * sWo[col] * acc  (scale matches flash's quantization).
// ---------------------------------------------------------------------------
__global__ __launch_bounds__(256, 2) void oproj_i8(
    const signed char* __restrict__ A8, const signed char* __restrict__ Wo8,
    const float* __restrict__ sWo, const unsigned* __restrict__ amaxp,
    float* __restrict__ out)
{
  constexpr int KS = 128;
  constexpr int TILEB = 192 * 128;            // 24576 B
  __shared__ __align__(16) signed char Ls[3 * TILEB];

  const int t = threadIdx.x, w = t >> 6, lane = t & 63;
  const int bid = blockIdx.x;                 // grid 512 = 8 xcd x 64
  const int s = (bid & 7) * 64 + (bid >> 3);
  const int bm = (s & 7) * 128, bn = (s >> 3) * 64;

  const signed char* gsrc[6];
  #pragma unroll
  for (int j = 0; j < 6; ++j) {
    int u = j * 256 + t;
    int R = u >> 3, slot = u & 7;
    int q = slot ^ (R & 7);                   // source k-chunk (16 i8 each)
    const signed char* base = (R < 128) ? A8 : Wo8;
    int rg = (R < 128) ? (bm + R) : (bn + (R - 128));
    gsrc[j] = base + (size_t)rg * DIMn + q * 16;
  }

  const int wr = w >> 1, wc = w & 1;
  const int rl = lane & 15, kh = lane >> 4;
  int aoff[4], boff[2];
  #pragma unroll
  for (int fm = 0; fm < 4; ++fm) {
    int R = wr * 64 + fm * 16 + rl;
    aoff[fm] = R * 128 + ((kh ^ (R & 7)) * 16);
  }
  #pragma unroll
  for (int fn = 0; fn < 2; ++fn) {
    int R = 128 + wc * 32 + fn * 16 + rl;
    boff[fn] = R * 128 + ((kh ^ (R & 7)) * 16);
  }

  i32x4 acc[4][2];
  #pragma unroll
  for (int i = 0; i < 4; ++i)
  #pragma unroll
    for (int j = 0; j < 2; ++j) acc[i][j] = (i32x4){0, 0, 0, 0};

  const int nt = DIMn / KS;                   // 32
  #pragma unroll
  for (int j = 0; j < 6; ++j) gload16(gsrc[j], &Ls[0 * TILEB + (j * 256 + t) * 16]);
  #pragma unroll
  for (int j = 0; j < 6; ++j) gload16(gsrc[j] + KS, &Ls[1 * TILEB + (j * 256 + t) * 16]);

  int cur = 0;
  for (int tt = 0; tt < nt; ++tt) {
    if (tt + 1 < nt) asm volatile("s_waitcnt vmcnt(6)" ::: "memory");
    else             asm volatile("s_waitcnt vmcnt(0)" ::: "memory");
    __builtin_amdgcn_s_barrier();
    __builtin_amdgcn_sched_barrier(0);

    int pre = cur + 2; if (pre >= 3) pre -= 3;
    if (tt + 2 < nt) {
      #pragma unroll
      for (int j = 0; j < 6; ++j)
        gload16(gsrc[j] + (size_t)(tt + 2) * KS, &Ls[pre * TILEB + (j * 256 + t) * 16]);
    }

    const signed char* Lp = &Ls[cur * TILEB];
    i32x4 a0[4], a1[4], b0[2], b1[2];
    #pragma unroll
    for (int fm = 0; fm < 4; ++fm) {
      a0[fm] = *(const i32x4*)(Lp + aoff[fm]);
      a1[fm] = *(const i32x4*)(Lp + (aoff[fm] ^ 64));   // k-slice 64..127
    }
    #pragma unroll
    for (int fn = 0; fn < 2; ++fn) {
      b0[fn] = *(const i32x4*)(Lp + boff[fn]);
      b1[fn] = *(const i32x4*)(Lp + (boff[fn] ^ 64));
    }
    __builtin_amdgcn_s_setprio(1);
    #pragma unroll
    for (int fm = 0; fm < 4; ++fm)
    #pragma unroll
      for (int fn = 0; fn < 2; ++fn) {
        acc[fm][fn] = __builtin_amdgcn_mfma_i32_16x16x64_i8(a0[fm], b0[fn], acc[fm][fn], 0, 0, 0);
        acc[fm][fn] = __builtin_amdgcn_mfma_i32_16x16x64_i8(a1[fm], b1[fn], acc[fm][fn], 0, 0, 0);
      }
    __builtin_amdgcn_s_setprio(0);
    cur += 1; if (cur >= 3) cur -= 3;
  }

  // epilogue: 16x16 C/D layout (m89); fold scales
  const float sAg = __builtin_bit_cast(float, *amaxp) * (1.0f / 127.0f);
  const int crow0 = bm + wr * 64 + kh * 4;
  #pragma unroll
  for (int fn = 0; fn < 2; ++fn) {
    const int col = bn + wc * 32 + fn * 16 + rl;
    const float sw = sWo[col] * sAg;
    #pragma unroll
    for (int fm = 0; fm < 4; ++fm)
    #pragma unroll
      for (int j = 0; j < 4; ++j)
        out[(size_t)(crow0 + fm * 16 + j) * DIMn + col] = sw * (float)acc[fm][fn][j];
  }
}

// ---------------------------------------------------------------------------
// Fallback GEMM (round-4, verbatim) — used only if ws_size is small.
// ---------------------------------------------------------------------------
template<bool SPLIT, int BN>
__global__ __launch_bounds__(256, 2) void gemm_mfma(
    const float* __restrict__ A,
    const float* __restrict__ W0, float* __restrict__ C0,
    const float* __restrict__ W1, float* __restrict__ C1,
    int Kd, int N)
{
  constexpr int BM = 64;
  constexpr int KSTEP = SPLIT ? 32 : 64;
  constexpr int CPR = SPLIT ? 4 : 8;
  constexpr int AUNITS = BM * KSTEP / 8;
  constexpr int UNITS  = (BM + BN) * KSTEP / 8;
  constexpr int UPT = UNITS / 256;
  constexpr int FN = BN / 32;
  constexpr int ROWS = BM + BN;

  __shared__ __align__(16) unsigned short Ls[2][ROWS * 64];

  const float* __restrict__ W = (blockIdx.z == 0) ? W0 : W1;
  float* __restrict__ Cp = (blockIdx.z == 0) ? C0 : C1;

  const int t  = threadIdx.x;
  const int bm = blockIdx.y * BM;
  const int bn = blockIdx.x * BN;

  const float* gsrc[UPT];
  int loff[UPT];
  #pragma unroll
  for (int i = 0; i < UPT; ++i) {
    int u = i * 256 + t;
    int row, c;
    if (u < AUNITS) {
      row = u / CPR; c = u % CPR;
      gsrc[i] = A + (size_t)(bm + row) * Kd + c * 8;
    } else {
      int v = u - AUNITS;
      int rr = v / CPR; c = v % CPR;
      row = BM + rr;
      gsrc[i] = W + (size_t)(bn + rr) * Kd + c * 8;
    }
    loff[i] = row * 64 + (c ^ (row & 7)) * 8;
  }

  const int lane = t & 63;
  const int w  = t >> 6;
  const int wr = w >> 1, wc = w & 1;
  const int rl = lane & 15, kh = lane >> 4;

  int aoff[2], boff[FN];
  #pragma unroll
  for (int fm = 0; fm < 2; ++fm) {
    int row = wr * 32 + fm * 16 + rl;
    aoff[fm] = row * 64 + (kh ^ (row & 7)) * 8;
  }
  #pragma unroll
  for (int fn = 0; fn < FN; ++fn) {
    int row = BM + wc * (BN / 2) + fn * 16 + rl;
    boff[fn] = row * 64 + (kh ^ (row & 7)) * 8;
  }

  f32x4 acc[2][FN];
  #pragma unroll
  for (int i = 0; i < 2; ++i)
  #pragma unroll
    for (int j = 0; j < FN; ++j) acc[i][j] = (f32x4){0.f, 0.f, 0.f, 0.f};

  float4 f0[UPT], f1[UPT];
  #pragma unroll
  for (int i = 0; i < UPT; ++i) {
    f0[i] = *(const float4*)(gsrc[i]);
    f1[i] = *(const float4*)(gsrc[i] + 4);
  }

  const int nt = Kd / KSTEP;
  for (int tt = 0; tt < nt; ++tt) {
    unsigned short* Lp = &Ls[tt & 1][0];
    #pragma unroll
    for (int i = 0; i < UPT; ++i) {
      float xv[8] = {f0[i].x, f0[i].y, f0[i].z, f0[i].w,
                     f1[i].x, f1[i].y, f1[i].z, f1[i].w};
      ushort8 hi, lo;
      #pragma unroll
      for (int j = 0; j < 8; ++j) {
        if constexpr (SPLIT) {
          unsigned short h_, l_;
          split_bf16(xv[j], h_, l_);
          hi[j] = h_; lo[j] = l_;
        } else {
          hi[j] = f2bf_rne(xv[j]);
          lo[j] = 0;
        }
      }
      *(ushort8*)(Lp + loff[i]) = hi;
      if constexpr (SPLIT)
        *(ushort8*)(((uintptr_t)(Lp + loff[i])) ^ 64) = lo;
    }
    if (tt + 1 < nt) {
      #pragma unroll
      for (int i = 0; i < UPT; ++i) {
        f0[i] = *(const float4*)(gsrc[i] + (size_t)(tt + 1) * KSTEP);
        f1[i] = *(const float4*)(gsrc[i] + (size_t)(tt + 1) * KSTEP + 4);
      }
    }
    __syncthreads();

    bf16x8 a0[2], a1[2], b0[FN], b1[FN];
    #pragma unroll
    for (int fm = 0; fm < 2; ++fm) {
      const unsigned short* p = Lp + aoff[fm];
      a0[fm] = *(const bf16x8*)p;
      a1[fm] = *(const bf16x8*)(((uintptr_t)p) ^ 64);
    }
    #pragma unroll
    for (int fn = 0; fn < FN; ++fn) {
      const unsigned short* p = Lp + boff[fn];
      b0[fn] = *(const bf16x8*)p;
      b1[fn] = *(const bf16x8*)(((uintptr_t)p) ^ 64);
    }
    #pragma unroll
    for (int fm = 0; fm < 2; ++fm)
    #pragma unroll
      for (int fn = 0; fn < FN; ++fn) {
        if constexpr (SPLIT) {
          acc[fm][fn] = __builtin_amdgcn_mfma_f32_16x16x32_bf16(a0[fm], b0[fn], acc[fm][fn], 0, 0, 0);
          acc[fm][fn] = __builtin_amdgcn_mfma_f32_16x16x32_bf16(a1[fm], b0[fn], acc[fm][fn], 0, 0, 0);
          acc[fm][fn] = __builtin_amdgcn_mfma_f32_16x16x32_bf16(a0[fm], b1[fn], acc[fm][fn], 0, 0, 0);
        } else {
          acc[fm][fn] = __builtin_amdgcn_mfma_f32_16x16x32_bf16(a0[fm], b0[fn], acc[fm][fn], 0, 0, 0);
          acc[fm][fn] = __builtin_amdgcn_mfma_f32_16x16x32_bf16(a1[fm], b1[fn], acc[fm][fn], 0, 0, 0);
        }
      }
  }

  const int crow0 = bm + wr * 32 + kh * 4;
  const int ccol0 = bn + wc * (BN / 2) + rl;
  #pragma unroll
  for (int fm = 0; fm < 2; ++fm)
  #pragma unroll
    for (int fn = 0; fn < FN; ++fn)
    #pragma unroll
      for (int j = 0; j < 4; ++j)
        Cp[(size_t)(crow0 + fm * 16 + j) * N + ccol0 + fn * 16] = acc[fm][fn][j];
}

// ---------------------------------------------------------------------------
// MFMA flash attention (r15, verbatim). I8OUT=true: bf16 V in, DIRECT i8
// attn-out with scale 127/amaxV (amaxV from vamax_k; |out| <= amaxV by
// convexity of softmax; clamp covers bf16 rounding overshoot).
// ---------------------------------------------------------------------------
#define KT 32

template<bool I8OUT>
__global__ __launch_bounds__(256, 2) void flash_attn_mfma(
    const float* __restrict__ Qg, const float* __restrict__ Kg, const void* __restrict__ Vgv,
    const float* __restrict__ fc, const float* __restrict__ fs,
    const int* __restrict__ sidx, void* __restrict__ Ov,
    const unsigned* __restrict__ amaxp)
{
  const int bid = blockIdx.x;
  const int qt = bid & 7;
  const int h  = (bid >> 3) & 31;
  const int b  = bid >> 8;
  const int q0 = qt * 64;
  const int hk = h >> 2;

  __shared__ __align__(16) unsigned short Ks[2][2][32][128];
  __shared__ __align__(16) unsigned short Vt[2][128][40];

  const int t = threadIdx.x;
  const int w = t >> 6;
  const int lane = t & 63;
  const int rl = lane & 15;
  const int kh = lane >> 4;

  const int qrow = q0 + w * 16 + rl;
  const int qp = sidx[qrow];

  int kr[2], kc_[2];
  #pragma unroll
  for (int i = 0; i < 2; ++i) { int u = i * 256 + t; kr[i] = u >> 4; kc_[i] = u & 15; }
  const int kkv = t >> 3, dcv = t & 7;

  const int nkt = (q0 + 64) / KT;
  const int qmaxw = q0 + w * 16 + 15;

  float kreg[2][8]; float4 kc4[2], ks4[2];
  float vregf[16];
  ushort8 vregu[2];

  #pragma unroll
  for (int i = 0; i < 2; ++i) {
    const float* kp_ = Kg + ((size_t)(b * Sn + kr[i]) * HKVn + hk) * HDn + kc_[i] * 8;
    *(float4*)&kreg[i][0] = *(const float4*)kp_;
    *(float4*)&kreg[i][4] = *(const float4*)(kp_ + 4);
    int posk = sidx[kr[i]];
    kc4[i] = *(const float4*)(fc + (size_t)posk * NPAIR + kc_[i] * 4);
    ks4[i] = *(const float4*)(fs + (size_t)posk * NPAIR + kc_[i] * 4);
  }
  if constexpr (I8OUT) {
    const unsigned short* vp_ = (const unsigned short*)Vgv +
        ((size_t)(b * Sn + kkv) * HKVn + hk) * HDn + dcv * 16;
    vregu[0] = *(const ushort8*)vp_;
    vregu[1] = *(const ushort8*)(vp_ + 8);
  } else {
    const float* vp_ = (const float*)Vgv + ((size_t)(b * Sn + kkv) * HKVn + hk) * HDn + dcv * 16;
    #pragma unroll
    for (int i = 0; i < 4; ++i) *(float4*)&vregf[i * 4] = *(const float4*)(vp_ + i * 4);
  }

  bf16x8 qh[4], ql[4];
  {
    const float* qptr = Qg + ((size_t)(b * Sn + qrow) * HQn + h) * HDn;
    #pragma unroll
    for (int ds = 0; ds < 4; ++ds) {
      int d0 = ds * 32 + kh * 8;
      float4 u0 = *(const float4*)(qptr + d0);
      float4 u1 = *(const float4*)(qptr + d0 + 4);
      float4 c4 = *(const float4*)(fc + (size_t)qp * NPAIR + d0 / 2);
      float4 s4 = *(const float4*)(fs + (size_t)qp * NPAIR + d0 / 2);
      float v[8];
      v[0] = u0.x * c4.x - u0.y * s4.x;  v[1] = u0.x * s4.x + u0.y * c4.x;
      v[2] = u0.z * c4.y - u0.w * s4.y;  v[3] = u0.z * s4.y + u0.w * c4.y;
      v[4] = u1.x * c4.z - u1.y * s4.z;  v[5] = u1.x * s4.z + u1.y * c4.z;
      v[6] = u1.z * c4.w - u1.w * s4.w;  v[7] = u1.z * s4.w + u1.w * c4.w;
      #pragma unroll
      for (int j = 0; j < 8; ++j) {
        unsigned short h_, l_;
        split_bf16(v[j], h_, l_);
        qh[ds][j] = (short)h_; ql[ds][j] = (short)l_;
      }
    }
  }

  float m_run = -3.0e38f, l_run = 0.f;
  f32x4 acc_o[8];
  #pragma unroll
  for (int i = 0; i < 8; ++i) acc_o[i] = (f32x4){0.f, 0.f, 0.f, 0.f};

  for (int tt = 0; tt < nkt; ++tt) {
    const int kbase = tt * KT;
    const int buf = tt & 1;

    #pragma unroll
    for (int i = 0; i < 2; ++i) {
      float rv[8];
      rv[0] = kreg[i][0] * kc4[i].x - kreg[i][1] * ks4[i].x;
      rv[1] = kreg[i][0] * ks4[i].x + kreg[i][1] * kc4[i].x;
      rv[2] = kreg[i][2] * kc4[i].y - kreg[i][3] * ks4[i].y;
      rv[3] = kreg[i][2] * ks4[i].y + kreg[i][3] * kc4[i].y;
      rv[4] = kreg[i][4] * kc4[i].z - kreg[i][5] * ks4[i].z;
      rv[5] = kreg[i][4] * ks4[i].z + kreg[i][5] * kc4[i].z;
      rv[6] = kreg[i][6] * kc4[i].w - kreg[i][7] * ks4[i].w;
      rv[7] = kreg[i][6] * ks4[i].w + kreg[i][7] * kc4[i].w;
      ushort8 hi, lo;
      #pragma unroll
      for (int j = 0; j < 8; ++j) {
        unsigned short h_, l_;
        split_bf16(rv[j], h_, l_);
        hi[j] = h_; lo[j] = l_;
      }
      int slot = kc_[i] ^ (kr[i] & 15);
      *(ushort8*)&Ks[buf][0][kr[i]][slot * 8] = hi;
      *(ushort8*)&Ks[buf][1][kr[i]][slot * 8] = lo;
    }
    if constexpr (I8OUT) {
      #pragma unroll
      for (int i = 0; i < 8; ++i) {
        Vt[buf][dcv * 16 + i][kkv] = vregu[0][i];
        Vt[buf][dcv * 16 + 8 + i][kkv] = vregu[1][i];
      }
    } else {
      #pragma unroll
      for (int i = 0; i < 16; ++i)
        Vt[buf][dcv * 16 + i][kkv] = f2bf_rne(vregf[i]);
    }

    if (tt + 1 < nkt) {
      const int kb = kbase + KT;
      #pragma unroll
      for (int i = 0; i < 2; ++i) {
        const float* kp_ = Kg + ((size_t)(b * Sn + kb + kr[i]) * HKVn + hk) * HDn + kc_[i] * 8;
        *(float4*)&kreg[i][0] = *(const float4*)kp_;
        *(float4*)&kreg[i][4] = *(const float4*)(kp_ + 4);
        int posk = sidx[kb + kr[i]];
        kc4[i] = *(const float4*)(fc + (size_t)posk * NPAIR + kc_[i] * 4);
        ks4[i] = *(const float4*)(fs + (size_t)posk * NPAIR + kc_[i] * 4);
      }
      if constexpr (I8OUT) {
        const unsigned short* vp_ = (const unsigned short*)Vgv +
            ((size_t)(b * Sn + kb + kkv) * HKVn + hk) * HDn + dcv * 16;
        vregu[0] = *(const ushort8*)vp_;
        vregu[1] = *(const ushort8*)(vp_ + 8);
      } else {
        const float* vp_ = (const float*)Vgv + ((size_t)(b * Sn + kb + kkv) * HKVn + hk) * HDn + dcv * 16;
        #pragma unroll
        for (int i = 0; i < 4; ++i) *(float4*)&vregf[i * 4] = *(const float4*)(vp_ + i * 4);
      }
    }
    __syncthreads();

    if (kbase > qmaxw) continue;

    float p[8];
    #pragma unroll
    for (int fm = 0; fm < 2; ++fm) {
      f32x4 accs = (f32x4){0.f, 0.f, 0.f, 0.f};
      #pragma unroll
      for (int ds = 0; ds < 4; ++ds) {
        int slot = (ds * 4 + kh) ^ rl;
        bf16x8 kH = *(const bf16x8*)&Ks[buf][0][fm * 16 + rl][slot * 8];
        bf16x8 kL = *(const bf16x8*)&Ks[buf][1][fm * 16 + rl][slot * 8];
        accs = __builtin_amdgcn_mfma_f32_16x16x32_bf16(kH, qh[ds], accs, 0, 0, 0);
        accs = __builtin_amdgcn_mfma_f32_16x16x32_bf16(kL, qh[ds], accs, 0, 0, 0);
        accs = __builtin_amdgcn_mfma_f32_16x16x32_bf16(kH, ql[ds], accs, 0, 0, 0);
      }
      #pragma unroll
      for (int r = 0; r < 4; ++r) {
        int kp = kbase + fm * 16 + kh * 4 + r;
        p[fm * 4 + r] = accs[r] * SCALE + ((kp <= qp) ? 0.f : -1.0e9f);
      }
    }

    float tmax = p[0];
    #pragma unroll
    for (int i = 1; i < 8; ++i) tmax = fmaxf(tmax, p[i]);
    tmax = fmaxf(tmax, __shfl_xor(tmax, 16));
    tmax = fmaxf(tmax, __shfl_xor(tmax, 32));
    float m_new = fmaxf(m_run, tmax);
    float crs = __expf(m_run - m_new);
    m_run = m_new;
    float tsum = 0.f;
    bf16x8 pa;
    #pragma unroll
    for (int i = 0; i < 8; ++i) {
      float ev = __expf(p[i] - m_new);
      tsum += ev;
      pa[i] = (short)f2bf_rne(ev);
    }
    tsum += __shfl_xor(tsum, 16);
    tsum += __shfl_xor(tsum, 32);
    l_run = l_run * crs + tsum;

    float cq[4];
    #pragma unroll
    for (int r = 0; r < 4; ++r) cq[r] = __shfl(crs, kh * 4 + r);

    #pragma unroll
    for (int db = 0; db < 8; ++db) {
      short4 v0 = *(const short4*)&Vt[buf][db * 16 + rl][kh * 4];
      short4 v1 = *(const short4*)&Vt[buf][db * 16 + rl][16 + kh * 4];
      bf16x8 vb = {v0.x, v0.y, v0.z, v0.w, v1.x, v1.y, v1.z, v1.w};
      f32x4 a = acc_o[db];
      a[0] *= cq[0]; a[1] *= cq[1]; a[2] *= cq[2]; a[3] *= cq[3];
      acc_o[db] = __builtin_amdgcn_mfma_f32_16x16x32_bf16(pa, vb, a, 0, 0, 0);
    }
  }

  float lq[4];
  #pragma unroll
  for (int r = 0; r < 4; ++r) lq[r] = 1.0f / __shfl(l_run, kh * 4 + r);
  float qinv = 0.f;
  if constexpr (I8OUT) {
    const float amv = __builtin_bit_cast(float, *amaxp);
    qinv = (amv > 0.f) ? 127.0f / amv : 0.f;
  }
  #pragma unroll
  for (int db = 0; db < 8; ++db)
  #pragma unroll
    for (int r = 0; r < 4; ++r) {
      int q = q0 + w * 16 + kh * 4 + r;
      size_t idx = ((size_t)(b * Sn + q) * HQn + h) * HDn + db * 16 + rl;
      float val = acc_o[db][r] * lq[r];
      if constexpr (I8OUT) {
        int qv = __float2int_rn(val * qinv);
        qv = qv > 127 ? 127 : (qv < -127 ? -127 : qv);
        ((signed char*)Ov)[idx] = (signed char)qv;
      } else {
        ((float*)Ov)[idx] = val;
      }
    }
}

// ---------------------------------------------------------------------------
extern "C" void kernel_launch(void* const* d_in, const int* in_sizes, int n_in,
                              void* d_out, int out_size, void* d_ws, size_t ws_size,
                              hipStream_t stream)
{
  const float* x    = (const float*)d_in[0];
  const float* fc   = (const float*)d_in[1];
  const float* fs   = (const float*)d_in[2];
  const int*   sidx = (const int*)d_in[5];
  const float* wq   = (const float*)d_in[6];
  const float* wk   = (const float*)d_in[7];
  const float* wv   = (const float*)d_in[8];
  const float* wo   = (const float*)d_in[9];
  float* out = (float*)d_out;

  const int M = Bn * Sn;                          // 1024
  const size_t EX  = (size_t)M * DIMn;            // 4,194,304 elems
  const size_t EW  = (size_t)DIMn * DIMn;         // 16,777,216
  const size_t EK  = (size_t)M * KVN;             // 1,048,576
  const size_t EW8 = (size_t)NALL * DIMn;         // 25.2 MB

  char* p = (char*)d_ws;
  signed char* xh8 = (signed char*)p;        p += EX;
  signed char* xl8 = (signed char*)p;        p += EX;
  signed char* wh8 = (signed char*)p;        p += EW8;
  signed char* wl8 = (signed char*)p;        p += EW8;
  signed char* wo8 = (signed char*)p;        p += EW;
  signed char* A8  = (signed char*)p;        p += EX;
  float* sA  = (float*)p;                    p += 1024 * 4;
  float* sW  = (float*)p;                    p += (size_t)NALL * 4;
  float* sWo = (float*)p;                    p += (size_t)DIMn * 4;
  unsigned* amaxp = (unsigned*)p;            p += 256;
  float* Qw = (float*)p;                     p += 4 * EX;
  float* Kw = (float*)p;                     p += 4 * EK;
  unsigned short* Vw = (unsigned short*)p;   p += 2 * EK;
  const size_t NEED = (size_t)(p - (char*)d_ws);  // ~107 MB

  if (ws_size >= NEED) {
    // quantize x + [wq|wk|wv] (split-i8) + wo (plain i8) + init V-amax
    quant_rows<<<1024 + NALL + DIMn, 256, 0, stream>>>(
        x, wq, wk, wv, wo, xh8, xl8, wh8, wl8, wo8, sA, sW, sWo, amaxp);
    // fused QKV projection, i8-split, 3-phase counted-vmcnt (r13 bit-exact)
    qkv_gemm_i8<<<512, 256, 0, stream>>>(
        xh8, xl8, wh8, wl8, sA, sW, Qw, Kw, Vw);
    // amax(V) -> amaxp (decoupled tiny reduce; 2 MB scan)
    vamax_k<<<512, 256, 0, stream>>>(Vw, amaxp, (int)(EK / 8));
    // flash attention (fused RoPE), DIRECT i8 attn-out (scale 127/amaxV)
    flash_attn_mfma<true><<<Bn * HQn * (Sn / 64), 256, 0, stream>>>(
        Qw, Kw, Vw, fc, fs, sidx, A8, amaxp);
    // O-proj: plain i8, KS=128, 3-buf counted-vmcnt -> d_out
    oproj_i8<<<512, 256, 0, stream>>>(A8, wo8, sWo, amaxp, out);
  } else {
    // fallback: round-4 path (40 MB ws)
    float* Qw2 = (float*)d_ws;
    float* Kw2 = Qw2 + (size_t)M * HQn * HDn;
    float* Vw2 = Kw2 + (size_t)M * HKVn * HDn;
    float* Aw2 = Vw2 + (size_t)M * HKVn * HDn;
    unsigned* dummyA = (unsigned*)(Aw2 + (size_t)M * HQn * HDn);
    gemm_mfma<true, 128><<<dim3(DIMn / 128, M / 64, 1), 256, 0, stream>>>(
        x, wq, Qw2, wq, Qw2, DIMn, DIMn);
    gemm_mfma<true, 64><<<dim3((HKVn * HDn) / 64, M / 64, 2), 256, 0, stream>>>(
        x, wk, Kw2, wv, Vw2, DIMn, HKVn * HDn);
    flash_attn_mfma<false><<<Bn * HQn * (Sn / 64), 256, 0, stream>>>(
        Qw2, Kw2, Vw2, fc, fs, sidx, Aw2, dummyA);
    gemm_mfma<false, 128><<<dim3(DIMn / 128, M / 64, 1), 256, 0, stream>>>(
        Aw2, wo, out, wo, out, DIMn, DIMn);
  }
}